// Round 9
// baseline (535.460 us; speedup 1.0000x reference)
//
#include <hip/hip_runtime.h>
#include <stdint.h>

#define NROWS 100000
#define SDIM 150
#define HDIM 150
#define NKB 20            // K-steps of 32 (K = 4 segs x 160 padded)
#define BM 64             // rows per block (shared by all 4 waves)
#define NTHREADS 256
#define CW 160            // cols per wave (block covers 4*160 = all 640)
#define BSLICE 40960      // bytes per K-step slice of packed W (640 cols * 64B)

using half8  = __attribute__((ext_vector_type(8))) _Float16;
using fp16x2 = __attribute__((ext_vector_type(2))) __fp16;
using floatx4 = __attribute__((ext_vector_type(4))) float;

__device__ __forceinline__ float fsig(float x) {
  return __builtin_amdgcn_rcpf(1.0f + __expf(-x));
}
__device__ __forceinline__ float ftanh(float x) {
  return 2.0f * __builtin_amdgcn_rcpf(1.0f + __expf(-2.0f * x)) - 1.0f;
}

// Pack W = [w_in; w_out; u_in; u_out] (600x600 f32) -> f16, k-blocked,
// h-major cols (col = h*4 + g), NO swizzle (read from global, not LDS):
//   byte(col,k) = kb*BSLICE + col*64 + kg*16 + j*2,  kb=k>>5, kg=(k>>3)&3, j=k&7
// zero-padded kl>=150 (per segment) and h>=150.
__global__ void pack_w_kernel(const float* __restrict__ w_in,
                              const float* __restrict__ w_out,
                              const float* __restrict__ u_in,
                              const float* __restrict__ u_out,
                              _Float16* __restrict__ wblk) {
  int idx = blockIdx.x * 256 + threadIdx.x;
  if (idx >= NKB * 640 * 32) return;
  int j   = idx & 7;
  int kg  = (idx >> 3) & 3;
  int col = (idx >> 5) % 640;
  int kb  = idx / (640 * 32);
  int k   = kb * 32 + kg * 8 + j;
  int seg = k / 160;
  int kl  = k - seg * 160;
  int g   = col & 3;         // 0=input 1=output 2=forget 3=update
  int h   = col >> 2;
  float v = 0.0f;
  if (kl < SDIM && h < HDIM) {
    const float* src = (seg == 0) ? w_in : (seg == 1) ? w_out
                     : (seg == 2) ? u_in : u_out;
    v = src[(g * SDIM + kl) * HDIM + h];
  }
  wblk[idx] = (_Float16)v;
}

// Barrier-free, LDS-free K-loop. Block = 64 rows x 640 cols, 4 waves;
// wave wid owns cols [wid*160, wid*160+160): acc[4][10] f32x4 = 160 VGPR.
// A read once from HBM per block (waves share rows -> L1/L2 hits);
// B fragments read per-wave from packed global (L2-resident, 1KB/load).
__global__ __launch_bounds__(NTHREADS, 2) void lstm_fused_kernel(
    const float* __restrict__ s_in, const float* __restrict__ s_out,
    const float* __restrict__ h_in, const float* __restrict__ h_out,
    const float* __restrict__ last_c, const float* __restrict__ bias,
    const _Float16* __restrict__ wblk,
    float* __restrict__ out_hid, float* __restrict__ out_cell) {
  __shared__ __align__(16) _Float16 ovl_all[4][1024];  // 8KB: epilogue overlay

  const int tid  = threadIdx.x;
  const int lane = tid & 63;
  const int l15  = lane & 15;
  const int kgrp = lane >> 4;
  const int wid  = tid >> 6;           // 0..3
  const int row0 = blockIdx.x * BM;

  const float* segp[4] = {s_in, s_out, h_in, h_out};

  // A row element-offsets (rows shared by all 4 waves; clamped at tail)
  int ro[4];
#pragma unroll
  for (int mt = 0; mt < 4; ++mt) {
    int r = row0 + mt * 16 + l15;
    ro[mt] = min(r, NROWS - 1) * SDIM;
  }

  floatx4 acc[4][10] = {};
  float4 pf[8];       // A(t+1) f32 in flight (4 mtiles x 32B/lane)
  half8  afh[4];      // A(t) f16 fragments
  half8  bfL[5], bfH[5];

  auto issueA = [&](int kb) {
    const int seg = kb / 5, kk = kb % 5;
#pragma unroll
    for (int mt = 0; mt < 4; ++mt) {
      const float* p = segp[seg] + ro[mt] + kk * 32 + kgrp * 8;
      if (kk < 4) {
        pf[2 * mt]     = *(const float4*)p;
        pf[2 * mt + 1] = *(const float4*)(p + 4);
      } else {
        // k-window 128..159 (valid < 150): kgrp0/1 full, kgrp2 6 valid, kgrp3 none
        if (kgrp < 2) {
          pf[2 * mt]     = *(const float4*)p;
          pf[2 * mt + 1] = *(const float4*)(p + 4);
        } else if (kgrp == 2) {
          pf[2 * mt] = *(const float4*)p;
          float2 t0 = *(const float2*)(p + 4);
          pf[2 * mt + 1] = make_float4(t0.x, t0.y, 0.f, 0.f);
        } else {
          pf[2 * mt]     = make_float4(0.f, 0.f, 0.f, 0.f);
          pf[2 * mt + 1] = make_float4(0.f, 0.f, 0.f, 0.f);
        }
      }
    }
  };
  auto cv = [&](const float4& lo, const float4& hi) -> half8 {
    union { fp16x2 h2[4]; half8 v; } u;
    u.h2[0] = __builtin_amdgcn_cvt_pkrtz(lo.x, lo.y);
    u.h2[1] = __builtin_amdgcn_cvt_pkrtz(lo.z, lo.w);
    u.h2[2] = __builtin_amdgcn_cvt_pkrtz(hi.x, hi.y);
    u.h2[3] = __builtin_amdgcn_cvt_pkrtz(hi.z, hi.w);
    return u.v;
  };
  auto cvtA = [&]() {
#pragma unroll
    for (int mt = 0; mt < 4; ++mt) afh[mt] = cv(pf[2 * mt], pf[2 * mt + 1]);
  };

  // B lane base: byte offset within one K-step slice
  const int bbase = (wid * CW + l15) * 64 + kgrp * 16;
  auto loadB = [&](half8* bf, int kb, int hf) {
    const char* g = (const char*)wblk + (size_t)kb * BSLICE + bbase + hf * 5120;
#pragma unroll
    for (int n = 0; n < 5; ++n) bf[n] = *(const half8*)(g + n * 1024);
  };

  // ---- prologue ----
  issueA(0);
  loadB(bfL, 0, 0);

  // ---- fully-unrolled barrier-free K-loop ----
#pragma unroll
  for (int kb = 0; kb < NKB; ++kb) {
    cvtA();                              // waits A(kb); frees pf
    if (kb + 1 < NKB) issueA(kb + 1);    // in flight across whole K-step
    loadB(bfH, kb, 1);                   // hi-half in flight under lo-MFMAs
    __builtin_amdgcn_s_setprio(1);
#pragma unroll
    for (int mt = 0; mt < 4; ++mt)
#pragma unroll
      for (int n = 0; n < 5; ++n)
        acc[mt][n] = __builtin_amdgcn_mfma_f32_16x16x32_f16(afh[mt], bfL[n], acc[mt][n], 0, 0, 0);
    __builtin_amdgcn_s_setprio(0);
    if (kb + 1 < NKB) loadB(bfL, kb + 1, 0);  // next lo in flight under hi-MFMAs
    __builtin_amdgcn_s_setprio(1);
#pragma unroll
    for (int mt = 0; mt < 4; ++mt)
#pragma unroll
      for (int n = 0; n < 5; ++n)
        acc[mt][n + 5] = __builtin_amdgcn_mfma_f32_16x16x32_f16(afh[mt], bfH[n], acc[mt][n + 5], 0, 0, 0);
    __builtin_amdgcn_s_setprio(0);
  }

  // ---- epilogue: wave-local gate exchange via 2KB overlay; no barriers ----
  _Float16* ovl = &ovl_all[wid][0];
#pragma unroll
  for (int nf = 0; nf < 10; ++nf) {
    int bcol = wid * CW + nf * 16 + l15;
    int bh = bcol >> 2, bg = bcol & 3;
    float bv = (bh < HDIM) ? bias[bg * HDIM + bh] : 0.f;
    asm volatile("s_waitcnt lgkmcnt(0)" ::: "memory");  // prev chunk reads done
#pragma unroll
    for (int mt = 0; mt < 4; ++mt)
#pragma unroll
      for (int i = 0; i < 4; ++i) {
        // C/D layout: col = lane&15, row = (lane>>4)*4 + i
        int rl = mt * 16 + kgrp * 4 + i;
        ovl[rl * 16 + l15] = (_Float16)fsig(acc[mt][nf][i] + bv);
      }
    asm volatile("s_waitcnt lgkmcnt(0)" ::: "memory");  // writes visible (wave-local)
    __builtin_amdgcn_sched_barrier(0);
    // consume: 64 rows x 2 h-pairs; 8 f16 = gates(i,o,f,u) @ h and h+1
#pragma unroll
    for (int it = 0; it < 2; ++it) {
      int row = it * 32 + (lane >> 1);
      int pr  = lane & 1;
      long nrow = (long)row0 + row;
      int hg = wid * 40 + nf * 4 + pr * 2;
      if (nrow < NROWS && hg < HDIM) {
        union { uint4 u; _Float16 f[8]; } gg;
        gg.u = *(const uint4*)(ovl + row * 16 + pr * 8);
        float2 lc = *(const float2*)(last_c + (size_t)nrow * HDIM + hg);
        float c0 = (float)gg.f[2] * lc.x + (float)gg.f[3] * (float)gg.f[0];
        float c1 = (float)gg.f[6] * lc.y + (float)gg.f[7] * (float)gg.f[4];
        float hd0 = (float)gg.f[1] * ftanh(c0);
        float hd1 = (float)gg.f[5] * ftanh(c1);
        *(float2*)(out_hid  + (size_t)nrow * HDIM + hg) = make_float2(hd0, hd1);
        *(float2*)(out_cell + (size_t)nrow * HDIM + hg) = make_float2(c0, c1);
      }
    }
  }
}

extern "C" void kernel_launch(void* const* d_in, const int* in_sizes, int n_in,
                              void* d_out, int out_size, void* d_ws, size_t ws_size,
                              hipStream_t stream) {
  const float* s_in   = (const float*)d_in[0];
  const float* s_out  = (const float*)d_in[1];
  const float* h_in   = (const float*)d_in[2];
  const float* h_out  = (const float*)d_in[3];
  const float* last_c = (const float*)d_in[4];
  const float* w_in   = (const float*)d_in[5];
  const float* w_out  = (const float*)d_in[6];
  const float* u_in   = (const float*)d_in[7];
  const float* u_out  = (const float*)d_in[8];
  const float* b      = (const float*)d_in[9];

  _Float16* wblk = (_Float16*)d_ws;  // 819200 B

  pack_w_kernel<<<(NKB * 640 * 32 + 255) / 256, 256, 0, stream>>>(
      w_in, w_out, u_in, u_out, wblk);

  float* out_hid  = (float*)d_out;
  float* out_cell = out_hid + (size_t)NROWS * HDIM;

  const int nrb = (NROWS + BM - 1) / BM;  // 1563
  lstm_fused_kernel<<<nrb, NTHREADS, 0, stream>>>(
      s_in, s_out, h_in, h_out, last_c, b, wblk, out_hid, out_cell);
}

// Round 10
// 416.447 us; speedup vs baseline: 1.2858x; 1.2858x over previous
//
#include <hip/hip_runtime.h>
#include <stdint.h>

#define NROWS 100000
#define SDIM 150
#define HDIM 150
#define NKB 20            // K-steps of 32 (K = 4 segs x 160 padded)
#define BM 64             // rows per block (shared by all 8 waves)
#define NTHREADS 512
#define CW 80             // cols per wave (8 waves cover all 640)
#define BSLICE 40960      // bytes per K-step slice of packed W (640 cols * 64B)
#define OVW 24            // overlay row stride in f16 (48B: 16B-aligned, 2-way banks)

using half8  = __attribute__((ext_vector_type(8))) _Float16;
using fp16x2 = __attribute__((ext_vector_type(2))) __fp16;
using floatx4 = __attribute__((ext_vector_type(4))) float;

__device__ __forceinline__ float fsig(float x) {
  return __builtin_amdgcn_rcpf(1.0f + __expf(-x));
}
__device__ __forceinline__ float ftanh(float x) {
  return 2.0f * __builtin_amdgcn_rcpf(1.0f + __expf(-2.0f * x)) - 1.0f;
}

// Pack W = [w_in; w_out; u_in; u_out] (600x600 f32) -> f16, k-blocked,
// h-major cols (col = h*4 + g), NO swizzle (consumed from global):
//   byte(col,k) = kb*BSLICE + col*64 + kg*16 + j*2,  kb=k>>5, kg=(k>>3)&3, j=k&7
// zero-padded kl>=150 (per segment) and h>=150.
__global__ void pack_w_kernel(const float* __restrict__ w_in,
                              const float* __restrict__ w_out,
                              const float* __restrict__ u_in,
                              const float* __restrict__ u_out,
                              _Float16* __restrict__ wblk) {
  int idx = blockIdx.x * 256 + threadIdx.x;
  if (idx >= NKB * 640 * 32) return;
  int j   = idx & 7;
  int kg  = (idx >> 3) & 3;
  int col = (idx >> 5) % 640;
  int kb  = idx / (640 * 32);
  int k   = kb * 32 + kg * 8 + j;
  int seg = k / 160;
  int kl  = k - seg * 160;
  int g   = col & 3;         // 0=input 1=output 2=forget 3=update
  int h   = col >> 2;
  float v = 0.0f;
  if (kl < SDIM && h < HDIM) {
    const float* src = (seg == 0) ? w_in : (seg == 1) ? w_out
                     : (seg == 2) ? u_in : u_out;
    v = src[(g * SDIM + kl) * HDIM + h];
  }
  wblk[idx] = (_Float16)v;
}

// Barrier-free, LDS-free K-loop. Block = 64 rows x 640 cols, 8 waves;
// wave wid owns cols [wid*80, wid*80+80): acc[4][5] f32x4 = 80 VGPR.
// A read once from HBM per block (waves share rows -> L1 hits);
// B fragments read per-wave from packed global (L2-resident, 1KB/load).
__global__ __launch_bounds__(NTHREADS, 2) void lstm_fused_kernel(
    const float* __restrict__ s_in, const float* __restrict__ s_out,
    const float* __restrict__ h_in, const float* __restrict__ h_out,
    const float* __restrict__ last_c, const float* __restrict__ bias,
    const _Float16* __restrict__ wblk,
    float* __restrict__ out_hid, float* __restrict__ out_cell) {
  __shared__ __align__(16) _Float16 ovl_all[8][BM * OVW];  // 24576 B

  const int tid  = threadIdx.x;
  const int lane = tid & 63;
  const int l15  = lane & 15;
  const int kgrp = lane >> 4;
  const int wid  = tid >> 6;           // 0..7
  const int row0 = blockIdx.x * BM;

  const float* segp[4] = {s_in, s_out, h_in, h_out};

  // A row element-offsets (rows shared by all waves; clamped at tail)
  int ro[4];
#pragma unroll
  for (int mt = 0; mt < 4; ++mt) {
    int r = row0 + mt * 16 + l15;
    ro[mt] = min(r, NROWS - 1) * SDIM;
  }

  floatx4 acc[4][5] = {};
  float4 pf[8];              // A(t) f32 in flight (4 mtiles x 32B/lane)
  half8  afh[4];             // A(t) f16 fragments
  half8  bfE[5], bfO[5];     // B even/odd K-step sets

  auto issueA = [&](int kb) {
    const int seg = kb / 5, kk = kb % 5;
#pragma unroll
    for (int mt = 0; mt < 4; ++mt) {
      const float* p = segp[seg] + ro[mt] + kk * 32 + kgrp * 8;
      if (kk < 4) {
        pf[2 * mt]     = *(const float4*)p;
        pf[2 * mt + 1] = *(const float4*)(p + 4);
      } else {
        // k-window 128..159 (valid < 150): kgrp0/1 full, kgrp2 6 valid, kgrp3 none
        if (kgrp < 2) {
          pf[2 * mt]     = *(const float4*)p;
          pf[2 * mt + 1] = *(const float4*)(p + 4);
        } else if (kgrp == 2) {
          pf[2 * mt] = *(const float4*)p;
          float2 t0 = *(const float2*)(p + 4);
          pf[2 * mt + 1] = make_float4(t0.x, t0.y, 0.f, 0.f);
        } else {
          pf[2 * mt]     = make_float4(0.f, 0.f, 0.f, 0.f);
          pf[2 * mt + 1] = make_float4(0.f, 0.f, 0.f, 0.f);
        }
      }
    }
  };
  auto cv = [&](const float4& lo, const float4& hi) -> half8 {
    union { fp16x2 h2[4]; half8 v; } u;
    u.h2[0] = __builtin_amdgcn_cvt_pkrtz(lo.x, lo.y);
    u.h2[1] = __builtin_amdgcn_cvt_pkrtz(lo.z, lo.w);
    u.h2[2] = __builtin_amdgcn_cvt_pkrtz(hi.x, hi.y);
    u.h2[3] = __builtin_amdgcn_cvt_pkrtz(hi.z, hi.w);
    return u.v;
  };
  auto cvtA = [&]() {
#pragma unroll
    for (int mt = 0; mt < 4; ++mt) afh[mt] = cv(pf[2 * mt], pf[2 * mt + 1]);
  };

  // B lane base: byte offset within one K-step slice
  const int bbase = (wid * CW + l15) * 64 + kgrp * 16;
  auto loadB = [&](half8* bf, int kb) {
    const char* g = (const char*)wblk + (size_t)kb * BSLICE + bbase;
#pragma unroll
    for (int n = 0; n < 5; ++n) bf[n] = *(const half8*)(g + n * 1024);
  };
  auto mfmaStep = [&](const half8* bf) {
    __builtin_amdgcn_s_setprio(1);
#pragma unroll
    for (int mt = 0; mt < 4; ++mt)
#pragma unroll
      for (int n = 0; n < 5; ++n)
        acc[mt][n] = __builtin_amdgcn_mfma_f32_16x16x32_f16(afh[mt], bf[n], acc[mt][n], 0, 0, 0);
    __builtin_amdgcn_s_setprio(0);
  };

  // ---- prologue ----
  issueA(0);
  loadB(bfE, 0);

  // ---- barrier-free K-loop; manual 2-step body (even/odd B-sets static) ----
#pragma unroll 1
  for (int t = 0; t < NKB; t += 2) {
    // step t (even): compute bfE, prefetch bfO(t+1), A(t+1)
    cvtA();                               // waits A(t); frees pf
    issueA(t + 1);                        // in flight across this step
    loadB(bfO, t + 1);                    // in flight under MFMAs
    mfmaStep(bfE);
    // step t+1 (odd): compute bfO, prefetch bfE(t+2), A(t+2)
    cvtA();                               // waits A(t+1)
    if (t + 2 < NKB) { issueA(t + 2); loadB(bfE, t + 2); }
    mfmaStep(bfO);
  }

  // ---- epilogue: wave-local gate exchange via overlay; no barriers ----
  _Float16* ovl = &ovl_all[wid][0];
#pragma unroll
  for (int nf = 0; nf < 5; ++nf) {
    int bcol = wid * CW + nf * 16 + l15;
    int bh = bcol >> 2, bg = bcol & 3;
    float bv = (bh < HDIM) ? bias[bg * HDIM + bh] : 0.f;
    asm volatile("s_waitcnt lgkmcnt(0)" ::: "memory");  // prev chunk reads done
#pragma unroll
    for (int mt = 0; mt < 4; ++mt)
#pragma unroll
      for (int i = 0; i < 4; ++i) {
        // C/D layout: col = lane&15, row = (lane>>4)*4 + i
        int rl = mt * 16 + kgrp * 4 + i;
        ovl[rl * OVW + l15] = (_Float16)fsig(acc[mt][nf][i] + bv);
      }
    asm volatile("s_waitcnt lgkmcnt(0)" ::: "memory");  // writes visible (wave-local)
    __builtin_amdgcn_sched_barrier(0);
    // consume: 64 rows x 2 h-pairs; 8 f16 = gates(i,o,f,u) @ h and h+1
#pragma unroll
    for (int it = 0; it < 2; ++it) {
      int row = it * 32 + (lane >> 1);
      int pr  = lane & 1;
      long nrow = (long)row0 + row;
      int hg = wid * 20 + nf * 4 + pr * 2;
      if (nrow < NROWS && hg < HDIM) {
        union { uint4 u; _Float16 f[8]; } gg;
        gg.u = *(const uint4*)(ovl + row * OVW + pr * 8);
        float2 lc = *(const float2*)(last_c + (size_t)nrow * HDIM + hg);
        float c0 = (float)gg.f[2] * lc.x + (float)gg.f[3] * (float)gg.f[0];
        float c1 = (float)gg.f[6] * lc.y + (float)gg.f[7] * (float)gg.f[4];
        float hd0 = (float)gg.f[1] * ftanh(c0);
        float hd1 = (float)gg.f[5] * ftanh(c1);
        *(float2*)(out_hid  + (size_t)nrow * HDIM + hg) = make_float2(hd0, hd1);
        *(float2*)(out_cell + (size_t)nrow * HDIM + hg) = make_float2(c0, c1);
      }
    }
  }
}

extern "C" void kernel_launch(void* const* d_in, const int* in_sizes, int n_in,
                              void* d_out, int out_size, void* d_ws, size_t ws_size,
                              hipStream_t stream) {
  const float* s_in   = (const float*)d_in[0];
  const float* s_out  = (const float*)d_in[1];
  const float* h_in   = (const float*)d_in[2];
  const float* h_out  = (const float*)d_in[3];
  const float* last_c = (const float*)d_in[4];
  const float* w_in   = (const float*)d_in[5];
  const float* w_out  = (const float*)d_in[6];
  const float* u_in   = (const float*)d_in[7];
  const float* u_out  = (const float*)d_in[8];
  const float* b      = (const float*)d_in[9];

  _Float16* wblk = (_Float16*)d_ws;  // 819200 B

  pack_w_kernel<<<(NKB * 640 * 32 + 255) / 256, 256, 0, stream>>>(
      w_in, w_out, u_in, u_out, wblk);

  float* out_hid  = (float*)d_out;
  float* out_cell = out_hid + (size_t)NROWS * HDIM;

  const int nrb = (NROWS + BM - 1) / BM;  // 1563
  lstm_fused_kernel<<<nrb, NTHREADS, 0, stream>>>(
      s_in, s_out, h_in, h_out, last_c, b, wblk, out_hid, out_cell);
}

// Round 11
// 385.337 us; speedup vs baseline: 1.3896x; 1.0807x over previous
//
#include <hip/hip_runtime.h>
#include <stdint.h>

#define NROWS 100000
#define SDIM 150
#define HDIM 150
#define NKB 20            // K-steps of 32 (K = 4 segs x 160 padded)
#define BM 64             // rows per block (shared by all 8 waves)
#define NTHREADS 512
#define CW 80             // cols per wave (8 waves cover all 640)
#define BSLICE 40960      // bytes per K-step slice of packed W (640 cols * 64B)
#define EPIW 648          // overlay stride in f16 (1296B: 16B-aligned, 2-way banks)

using half8  = __attribute__((ext_vector_type(8))) _Float16;
using fp16x2 = __attribute__((ext_vector_type(2))) __fp16;
using floatx4 = __attribute__((ext_vector_type(4))) float;

__device__ __forceinline__ float fsig(float x) {
  return __builtin_amdgcn_rcpf(1.0f + __expf(-x));
}
__device__ __forceinline__ float ftanh(float x) {
  return 2.0f * __builtin_amdgcn_rcpf(1.0f + __expf(-2.0f * x)) - 1.0f;
}

// Pack W = [w_in; w_out; u_in; u_out] (600x600 f32) -> f16, k-blocked,
// h-major cols (col = h*4 + g), NO swizzle (consumed from global):
//   byte(col,k) = kb*BSLICE + col*64 + kg*16 + j*2,  kb=k>>5, kg=(k>>3)&3, j=k&7
// zero-padded kl>=150 (per segment) and h>=150.
__global__ void pack_w_kernel(const float* __restrict__ w_in,
                              const float* __restrict__ w_out,
                              const float* __restrict__ u_in,
                              const float* __restrict__ u_out,
                              _Float16* __restrict__ wblk) {
  int idx = blockIdx.x * 256 + threadIdx.x;
  if (idx >= NKB * 640 * 32) return;
  int j   = idx & 7;
  int kg  = (idx >> 3) & 3;
  int col = (idx >> 5) % 640;
  int kb  = idx / (640 * 32);
  int k   = kb * 32 + kg * 8 + j;
  int seg = k / 160;
  int kl  = k - seg * 160;
  int g   = col & 3;         // 0=input 1=output 2=forget 3=update
  int h   = col >> 2;
  float v = 0.0f;
  if (kl < SDIM && h < HDIM) {
    const float* src = (seg == 0) ? w_in : (seg == 1) ? w_out
                     : (seg == 2) ? u_in : u_out;
    v = src[(g * SDIM + kl) * HDIM + h];
  }
  wblk[idx] = (_Float16)v;
}

// Barrier-free, LDS-free K-loop (R10, unchanged). Block = 64 rows x 640 cols,
// 8 waves; wave wid owns cols [wid*80, wid*80+80): acc[4][5] f32x4 = 80 AGPR.
// Epilogue: block-coalesced via shared 32-row overlay (R1-proven write path).
__global__ __launch_bounds__(NTHREADS, 2) void lstm_fused_kernel(
    const float* __restrict__ s_in, const float* __restrict__ s_out,
    const float* __restrict__ h_in, const float* __restrict__ h_out,
    const float* __restrict__ last_c, const float* __restrict__ bias,
    const _Float16* __restrict__ wblk,
    float* __restrict__ out_hid, float* __restrict__ out_cell) {
  __shared__ __align__(16) _Float16 epi[32 * EPIW];  // 41472 B

  const int tid  = threadIdx.x;
  const int lane = tid & 63;
  const int l15  = lane & 15;
  const int kgrp = lane >> 4;
  const int wid  = tid >> 6;           // 0..7
  const int row0 = blockIdx.x * BM;

  const float* segp[4] = {s_in, s_out, h_in, h_out};

  // A row element-offsets (rows shared by all waves; clamped at tail)
  int ro[4];
#pragma unroll
  for (int mt = 0; mt < 4; ++mt) {
    int r = row0 + mt * 16 + l15;
    ro[mt] = min(r, NROWS - 1) * SDIM;
  }

  floatx4 acc[4][5] = {};
  float4 pf[8];              // A(t) f32 in flight (4 mtiles x 32B/lane)
  half8  afh[4];             // A(t) f16 fragments
  half8  bfE[5], bfO[5];     // B even/odd K-step sets

  auto issueA = [&](int kb) {
    const int seg = kb / 5, kk = kb % 5;
#pragma unroll
    for (int mt = 0; mt < 4; ++mt) {
      const float* p = segp[seg] + ro[mt] + kk * 32 + kgrp * 8;
      if (kk < 4) {
        pf[2 * mt]     = *(const float4*)p;
        pf[2 * mt + 1] = *(const float4*)(p + 4);
      } else {
        // k-window 128..159 (valid < 150): kgrp0/1 full, kgrp2 6 valid, kgrp3 none
        if (kgrp < 2) {
          pf[2 * mt]     = *(const float4*)p;
          pf[2 * mt + 1] = *(const float4*)(p + 4);
        } else if (kgrp == 2) {
          pf[2 * mt] = *(const float4*)p;
          float2 t0 = *(const float2*)(p + 4);
          pf[2 * mt + 1] = make_float4(t0.x, t0.y, 0.f, 0.f);
        } else {
          pf[2 * mt]     = make_float4(0.f, 0.f, 0.f, 0.f);
          pf[2 * mt + 1] = make_float4(0.f, 0.f, 0.f, 0.f);
        }
      }
    }
  };
  auto cv = [&](const float4& lo, const float4& hi) -> half8 {
    union { fp16x2 h2[4]; half8 v; } u;
    u.h2[0] = __builtin_amdgcn_cvt_pkrtz(lo.x, lo.y);
    u.h2[1] = __builtin_amdgcn_cvt_pkrtz(lo.z, lo.w);
    u.h2[2] = __builtin_amdgcn_cvt_pkrtz(hi.x, hi.y);
    u.h2[3] = __builtin_amdgcn_cvt_pkrtz(hi.z, hi.w);
    return u.v;
  };
  auto cvtA = [&]() {
#pragma unroll
    for (int mt = 0; mt < 4; ++mt) afh[mt] = cv(pf[2 * mt], pf[2 * mt + 1]);
  };

  // B lane base: byte offset within one K-step slice
  const int bbase = (wid * CW + l15) * 64 + kgrp * 16;
  auto loadB = [&](half8* bf, int kb) {
    const char* g = (const char*)wblk + (size_t)kb * BSLICE + bbase;
#pragma unroll
    for (int n = 0; n < 5; ++n) bf[n] = *(const half8*)(g + n * 1024);
  };
  auto mfmaStep = [&](const half8* bf) {
    __builtin_amdgcn_s_setprio(1);
#pragma unroll
    for (int mt = 0; mt < 4; ++mt)
#pragma unroll
      for (int n = 0; n < 5; ++n)
        acc[mt][n] = __builtin_amdgcn_mfma_f32_16x16x32_f16(afh[mt], bf[n], acc[mt][n], 0, 0, 0);
    __builtin_amdgcn_s_setprio(0);
  };

  // ---- prologue ----
  issueA(0);
  loadB(bfE, 0);

  // ---- barrier-free K-loop; manual 2-step body (even/odd B-sets static) ----
#pragma unroll 1
  for (int t = 0; t < NKB; t += 2) {
    // step t (even): compute bfE, prefetch bfO(t+1), A(t+1)
    cvtA();                               // waits A(t); frees pf
    issueA(t + 1);                        // in flight across this step
    loadB(bfO, t + 1);                    // in flight under MFMAs
    mfmaStep(bfE);
    // step t+1 (odd): compute bfO, prefetch bfE(t+2), A(t+2)
    cvtA();                               // waits A(t+1)
    if (t + 2 < NKB) { issueA(t + 2); loadB(bfE, t + 2); }
    mfmaStep(bfO);
  }

  // ---- bias fragments ----
  float bfrag[5];
#pragma unroll
  for (int nf = 0; nf < 5; ++nf) {
    int bcol = wid * CW + nf * 16 + l15;
    int bh = bcol >> 2, bg = bcol & 3;
    bfrag[nf] = (bh < HDIM) ? bias[bg * HDIM + bh] : 0.f;
  }

  // ---- epilogue: 2 chunks of 32 rows; block-coalesced consumer ----
#pragma unroll
  for (int c = 0; c < 2; ++c) {
    if (c) __syncthreads();  // previous chunk consumed
    // produce: all waves write their gate cols for rows [c*32, c*32+32)
#pragma unroll
    for (int mt2 = 0; mt2 < 2; ++mt2) {
      const int mt = c * 2 + mt2;
#pragma unroll
      for (int nf = 0; nf < 5; ++nf) {
        int colb = wid * CW + nf * 16 + l15;
#pragma unroll
        for (int i = 0; i < 4; ++i) {
          // C/D layout: col = lane&15, row = (lane>>4)*4 + i
          int rl = mt2 * 16 + kgrp * 4 + i;
          epi[rl * EPIW + colb] = (_Float16)fsig(acc[mt][nf][i] + bfrag[nf]);
        }
      }
    }
    __syncthreads();
    // consume: idx -> (row, h-pair); 75 consecutive threads = one 600B row
#pragma unroll
    for (int it = 0; it < 5; ++it) {
      int idx = tid + it * NTHREADS;
      if (idx < 32 * 75) {
        int row = idx / 75;
        int h2  = idx - row * 75;
        long nrow = (long)row0 + c * 32 + row;
        if (nrow < NROWS) {
          int h = h2 * 2;
          union { uint4 u; _Float16 f[8]; } gg;  // [i,o,f,u]@h, [i,o,f,u]@h+1
          gg.u = *(const uint4*)(epi + row * EPIW + h2 * 8);
          float2 lc = *(const float2*)(last_c + (size_t)nrow * HDIM + h);
          float c0 = (float)gg.f[2] * lc.x + (float)gg.f[3] * (float)gg.f[0];
          float c1 = (float)gg.f[6] * lc.y + (float)gg.f[7] * (float)gg.f[4];
          float hd0 = (float)gg.f[1] * ftanh(c0);
          float hd1 = (float)gg.f[5] * ftanh(c1);
          *(float2*)(out_hid  + (size_t)nrow * HDIM + h) = make_float2(hd0, hd1);
          *(float2*)(out_cell + (size_t)nrow * HDIM + h) = make_float2(c0, c1);
        }
      }
    }
  }
}

extern "C" void kernel_launch(void* const* d_in, const int* in_sizes, int n_in,
                              void* d_out, int out_size, void* d_ws, size_t ws_size,
                              hipStream_t stream) {
  const float* s_in   = (const float*)d_in[0];
  const float* s_out  = (const float*)d_in[1];
  const float* h_in   = (const float*)d_in[2];
  const float* h_out  = (const float*)d_in[3];
  const float* last_c = (const float*)d_in[4];
  const float* w_in   = (const float*)d_in[5];
  const float* w_out  = (const float*)d_in[6];
  const float* u_in   = (const float*)d_in[7];
  const float* u_out  = (const float*)d_in[8];
  const float* b      = (const float*)d_in[9];

  _Float16* wblk = (_Float16*)d_ws;  // 819200 B

  pack_w_kernel<<<(NKB * 640 * 32 + 255) / 256, 256, 0, stream>>>(
      w_in, w_out, u_in, u_out, wblk);

  float* out_hid  = (float*)d_out;
  float* out_cell = out_hid + (size_t)NROWS * HDIM;

  const int nrb = (NROWS + BM - 1) / BM;  // 1563
  lstm_fused_kernel<<<nrb, NTHREADS, 0, stream>>>(
      s_in, s_out, h_in, h_out, last_c, b, wblk, out_hid, out_cell);
}

// Round 12
// 227.053 us; speedup vs baseline: 2.3583x; 1.6971x over previous
//
#include <hip/hip_runtime.h>
#include <stdint.h>

#define NROWS 100000
#define SDIM 150
#define HDIM 150
#define NKB 20            // K-steps of 32 (K = 4 segs x 160 padded)
#define BM 64             // rows per block
#define NTHREADS 256      // 4 waves
#define CW 160            // cols per wave (4 waves cover all 640)
#define BSLICE 40960      // bytes per K-step slice of packed W (640 cols * 64B)
#define ASLICE 4096       // A f16 bytes per K-step in LDS (64 rows * 64B)
#define EPIW 648          // epilogue overlay stride in f16

using half8  = __attribute__((ext_vector_type(8))) _Float16;
using fp16x2 = __attribute__((ext_vector_type(2))) __fp16;
using floatx4 = __attribute__((ext_vector_type(4))) float;

__device__ __forceinline__ float fsig(float x) {
  return __builtin_amdgcn_rcpf(1.0f + __expf(-x));
}
__device__ __forceinline__ float ftanh(float x) {
  return 2.0f * __builtin_amdgcn_rcpf(1.0f + __expf(-2.0f * x)) - 1.0f;
}

// Pack W = [w_in; w_out; u_in; u_out] (600x600 f32) -> f16, k-blocked,
// h-major cols (col = h*4 + g), NO swizzle (consumed from global):
//   byte(col,k) = kb*BSLICE + col*64 + kg*16 + j*2,  kb=k>>5, kg=(k>>3)&3, j=k&7
__global__ void pack_w_kernel(const float* __restrict__ w_in,
                              const float* __restrict__ w_out,
                              const float* __restrict__ u_in,
                              const float* __restrict__ u_out,
                              _Float16* __restrict__ wblk) {
  int idx = blockIdx.x * 256 + threadIdx.x;
  if (idx >= NKB * 640 * 32) return;
  int j   = idx & 7;
  int kg  = (idx >> 3) & 3;
  int col = (idx >> 5) % 640;
  int kb  = idx / (640 * 32);
  int k   = kb * 32 + kg * 8 + j;
  int seg = k / 160;
  int kl  = k - seg * 160;
  int g   = col & 3;         // 0=input 1=output 2=forget 3=update
  int h   = col >> 2;
  float v = 0.0f;
  if (kl < SDIM && h < HDIM) {
    const float* src = (seg == 0) ? w_in : (seg == 1) ? w_out
                     : (seg == 2) ? u_in : u_out;
    v = src[(g * SDIM + kl) * HDIM + h];
  }
  wblk[idx] = (_Float16)v;
}

// Block = 64 rows x 640 cols, 4 waves; wave owns 64 x 160 (acc[4][10]).
// Prologue: ALL of A (64x640 f16, 80KB) staged to LDS once; ONE barrier.
// K-loop: 10 B-loads (L2) + 4 ds_reads + 40 MFMA per step; no barriers,
// no global A traffic, no ds_writes. Self-paced waves; 2 blocks/CU.
__global__ __launch_bounds__(NTHREADS, 2) void lstm_fused_kernel(
    const float* __restrict__ s_in, const float* __restrict__ s_out,
    const float* __restrict__ h_in, const float* __restrict__ h_out,
    const float* __restrict__ last_c, const float* __restrict__ bias,
    const _Float16* __restrict__ wblk,
    float* __restrict__ out_hid, float* __restrict__ out_cell) {
  __shared__ __align__(16) char lds[NKB * ASLICE];  // 81920 B (A image; epi aliases)

  const int tid  = threadIdx.x;
  const int lane = tid & 63;
  const int l15  = lane & 15;
  const int kgrp = lane >> 4;
  const int wid  = tid >> 6;           // 0..3
  const int row0 = blockIdx.x * BM;

  const float* segp[4] = {s_in, s_out, h_in, h_out};

  // ---- prologue: stage A[64 rows][640 k] as f16 into LDS, k-blocked ----
  // thread -> row = tid>>2 (0..63), 16B-chunk q = tid&3
  {
    const int a_row = tid >> 2;
    const int a_q   = tid & 3;
    const long n_a  = (long)min(row0 + a_row, NROWS - 1);
    const float* base = nullptr;  // per-kb
    const int a_off = a_row * 64 + ((a_q ^ ((a_row >> 1) & 3)) * 16);
#pragma unroll 5
    for (int kb = 0; kb < NKB; ++kb) {
      const int seg = kb / 5;
      const int kls = (kb % 5) * 32 + a_q * 8;
      float4 lo = make_float4(0.f, 0.f, 0.f, 0.f);
      float4 hi = make_float4(0.f, 0.f, 0.f, 0.f);
      const float* p = segp[seg] + (size_t)n_a * SDIM + kls;
      if (kls + 7 < SDIM) {
        lo = *(const float4*)p;
        hi = *(const float4*)(p + 4);
      } else if (kls < SDIM) {
        lo = *(const float4*)p;                 // k 144..147
        float2 t0 = *(const float2*)(p + 4);    // k 148,149
        hi = make_float4(t0.x, t0.y, 0.f, 0.f);
      }
      union { fp16x2 h2[4]; uint4 u; } pk;
      pk.h2[0] = __builtin_amdgcn_cvt_pkrtz(lo.x, lo.y);
      pk.h2[1] = __builtin_amdgcn_cvt_pkrtz(lo.z, lo.w);
      pk.h2[2] = __builtin_amdgcn_cvt_pkrtz(hi.x, hi.y);
      pk.h2[3] = __builtin_amdgcn_cvt_pkrtz(hi.z, hi.w);
      *(uint4*)(lds + kb * ASLICE + a_off) = pk.u;
    }
  }
  __syncthreads();  // A image complete; only barrier before epilogue

  // per-lane A fragment offsets (within one ASLICE)
  int aoff[4];
#pragma unroll
  for (int mt = 0; mt < 4; ++mt) {
    int r = mt * 16 + l15;
    aoff[mt] = r * 64 + ((kgrp ^ ((r >> 1) & 3)) * 16);
  }

  floatx4 acc[4][10] = {};

  // B lane base: byte offset within one K-step slice
  const char* wb = (const char*)wblk + ((wid * CW + l15) * 64 + kgrp * 16);

  // ---- barrier-free K-loop ----
#pragma unroll 1
  for (int kb = 0; kb < NKB; ++kb) {
    const char* g = wb + (size_t)kb * BSLICE;
    half8 bf0 = *(const half8*)(g);
    half8 bf1 = *(const half8*)(g + 1024);
    half8 bf2 = *(const half8*)(g + 2048);
    half8 bf3 = *(const half8*)(g + 3072);
    half8 bf4 = *(const half8*)(g + 4096);
    half8 bf5 = *(const half8*)(g + 5120);
    half8 bf6 = *(const half8*)(g + 6144);
    half8 bf7 = *(const half8*)(g + 7168);
    half8 bf8 = *(const half8*)(g + 8192);
    half8 bf9 = *(const half8*)(g + 9216);
    const char* ak = lds + kb * ASLICE;
    half8 af0 = *(const half8*)(ak + aoff[0]);
    half8 af1 = *(const half8*)(ak + aoff[1]);
    half8 af2 = *(const half8*)(ak + aoff[2]);
    half8 af3 = *(const half8*)(ak + aoff[3]);
    __builtin_amdgcn_s_setprio(1);
#define MF(MT, AF) \
    acc[MT][0] = __builtin_amdgcn_mfma_f32_16x16x32_f16(AF, bf0, acc[MT][0], 0, 0, 0); \
    acc[MT][1] = __builtin_amdgcn_mfma_f32_16x16x32_f16(AF, bf1, acc[MT][1], 0, 0, 0); \
    acc[MT][2] = __builtin_amdgcn_mfma_f32_16x16x32_f16(AF, bf2, acc[MT][2], 0, 0, 0); \
    acc[MT][3] = __builtin_amdgcn_mfma_f32_16x16x32_f16(AF, bf3, acc[MT][3], 0, 0, 0); \
    acc[MT][4] = __builtin_amdgcn_mfma_f32_16x16x32_f16(AF, bf4, acc[MT][4], 0, 0, 0); \
    acc[MT][5] = __builtin_amdgcn_mfma_f32_16x16x32_f16(AF, bf5, acc[MT][5], 0, 0, 0); \
    acc[MT][6] = __builtin_amdgcn_mfma_f32_16x16x32_f16(AF, bf6, acc[MT][6], 0, 0, 0); \
    acc[MT][7] = __builtin_amdgcn_mfma_f32_16x16x32_f16(AF, bf7, acc[MT][7], 0, 0, 0); \
    acc[MT][8] = __builtin_amdgcn_mfma_f32_16x16x32_f16(AF, bf8, acc[MT][8], 0, 0, 0); \
    acc[MT][9] = __builtin_amdgcn_mfma_f32_16x16x32_f16(AF, bf9, acc[MT][9], 0, 0, 0);
    MF(0, af0)
    MF(1, af1)
    MF(2, af2)
    MF(3, af3)
#undef MF
    __builtin_amdgcn_s_setprio(0);
  }

  // ---- bias fragments ----
  float bfrag[10];
#pragma unroll
  for (int nf = 0; nf < 10; ++nf) {
    int bcol = wid * CW + nf * 16 + l15;
    int bh = bcol >> 2, bg = bcol & 3;
    bfrag[nf] = (bh < HDIM) ? bias[bg * HDIM + bh] : 0.f;
  }

  // ---- epilogue: 4 chunks of 16 rows (chunk c = acc[c]); overlay aliases A ----
  _Float16* epi = (_Float16*)lds;  // 16 * 648 * 2 = 20736 B
#pragma unroll
  for (int c = 0; c < 4; ++c) {
    __syncthreads();  // A reads (c=0) / previous chunk consume done
#pragma unroll
    for (int nf = 0; nf < 10; ++nf) {
      int colb = wid * CW + nf * 16 + l15;
#pragma unroll
      for (int i = 0; i < 4; ++i) {
        // C/D layout: col = lane&15, row = (lane>>4)*4 + i  (rows c*16..c*16+15)
        int rl = kgrp * 4 + i;
        epi[rl * EPIW + colb] = (_Float16)fsig(acc[c][nf][i] + bfrag[nf]);
      }
    }
    __syncthreads();
    // consume: idx -> (row, h-pair); 75 consecutive threads = one 600B row
#pragma unroll
    for (int it = 0; it < 5; ++it) {
      int idx = tid + it * NTHREADS;
      if (idx < 16 * 75) {
        int row = idx / 75;
        int h2  = idx - row * 75;
        long nrow = (long)row0 + c * 16 + row;
        if (nrow < NROWS) {
          int h = h2 * 2;
          union { uint4 u; _Float16 f[8]; } gg;  // [i,o,f,u]@h, [i,o,f,u]@h+1
          gg.u = *(const uint4*)(epi + row * EPIW + h2 * 8);
          float2 lc = *(const float2*)(last_c + (size_t)nrow * HDIM + h);
          float c0 = (float)gg.f[2] * lc.x + (float)gg.f[3] * (float)gg.f[0];
          float c1 = (float)gg.f[6] * lc.y + (float)gg.f[7] * (float)gg.f[4];
          float hd0 = (float)gg.f[1] * ftanh(c0);
          float hd1 = (float)gg.f[5] * ftanh(c1);
          *(float2*)(out_hid  + (size_t)nrow * HDIM + h) = make_float2(hd0, hd1);
          *(float2*)(out_cell + (size_t)nrow * HDIM + h) = make_float2(c0, c1);
        }
      }
    }
  }
}

extern "C" void kernel_launch(void* const* d_in, const int* in_sizes, int n_in,
                              void* d_out, int out_size, void* d_ws, size_t ws_size,
                              hipStream_t stream) {
  const float* s_in   = (const float*)d_in[0];
  const float* s_out  = (const float*)d_in[1];
  const float* h_in   = (const float*)d_in[2];
  const float* h_out  = (const float*)d_in[3];
  const float* last_c = (const float*)d_in[4];
  const float* w_in   = (const float*)d_in[5];
  const float* w_out  = (const float*)d_in[6];
  const float* u_in   = (const float*)d_in[7];
  const float* u_out  = (const float*)d_in[8];
  const float* b      = (const float*)d_in[9];

  _Float16* wblk = (_Float16*)d_ws;  // 819200 B

  pack_w_kernel<<<(NKB * 640 * 32 + 255) / 256, 256, 0, stream>>>(
      w_in, w_out, u_in, u_out, wblk);

  float* out_hid  = (float*)d_out;
  float* out_cell = out_hid + (size_t)NROWS * HDIM;

  const int nrb = (NROWS + BM - 1) / BM;  // 1563
  lstm_fused_kernel<<<nrb, NTHREADS, 0, stream>>>(
      s_in, s_out, h_in, h_out, last_c, b, wblk, out_hid, out_cell);
}